// Round 11
// baseline (128.938 us; speedup 1.0000x reference)
//
#include <hip/hip_runtime.h>
#include <math.h>

// Tensor-field-network decoder: B=2, N=192, 3 conv layers (2 gated + 1 final).
// Round-11: r10 + alignment-native P3 for L1/L2: 320-thread blocks, 8x40
// groups of 4x4 register tiles -> T-read is ONE aligned ds_read_b128
// (was 5 floats at cg*5, ~3-5 LDS instrs). P3 per-wave instrs -31%.
// Guarded M-write discards the 16 padding columns. L0 keeps the proven
// 256-mapping. Same math order -> bit-identical output.
// Fallback to verified round-1 monolithic kernels if ws too small.

#define NN 192
#define BB 2
#define SPLIT 8
#define NS 24
#define NBASIS 10
#define HHID 32

__device__ __forceinline__ float relu_r(float x) {
    return fmaxf(x, 0.0f) * 1.4142135623730951f;
}
__device__ __forceinline__ float sigmoid_r(float x) {
    return (1.0f / (1.0f + expf(-x))) * 1.84623f;
}
__device__ __forceinline__ float dot4(float4 a, float4 b) {
    return a.x * b.x + a.y * b.y + a.z * b.z + a.w * b.w;
}

#define S_SCALE 0.07216878364870323f   // 1/sqrt(192)
#define ISQ10   0.31622776601683794f   // 1/sqrt(10)
#define I32     0.1767766952966369f    // 1/sqrt(32)

// ---------------------------------------------------------------------------
// tfn_act: per-atom sum of 8 split partials + activation + gating + scale.
// ---------------------------------------------------------------------------
__global__ __launch_bounds__(256) void tfn_act(
    const float* __restrict__ part, float* __restrict__ fa0, float* __restrict__ fa1)
{
    int t = blockIdx.x * 256 + threadIdx.x;     // < B*N*40
    if (t >= BB * NN * 40) return;
    int atom = t / 40, c = t - atom * 40;
    const float* p = &part[atom * SPLIT * 48];
    if (c < 16) {
        float s = 0.0f;
#pragma unroll
        for (int sp = 0; sp < SPLIT; ++sp) s += p[sp * 48 + c];
        fa0[atom * 16 + c] = relu_r(s) * S_SCALE;
    } else {
        int j = c - 16, u = j & 7;
        float g = 0.0f, v = 0.0f;
#pragma unroll
        for (int sp = 0; sp < SPLIT; ++sp) {
            g += p[sp * 48 + 16 + u];
            v += p[sp * 48 + 24 + j];
        }
        fa1[atom * 24 + j] = v * sigmoid_r(g) * S_SCALE;
    }
}

template <int LAYER>
__global__ __launch_bounds__(320, 4) void tfn_s1(
    const float* __restrict__ fin0,  // L0: features [B,N,16]; L1/2: fa0 [B*N,16]
    const float* __restrict__ fin1,  // L1/2: fa1 [B*N,24]
    const float* __restrict__ geo,   // [B,N,3]
    const float* __restrict__ w0g,   // [10,32]
    const float* __restrict__ b0g,   // [32]
    const float* __restrict__ wout,  // [32, TW]
    float* __restrict__ part)        // [B*N*SPLIT, NOUT]
{
    constexpr int NT    = (LAYER == 0) ? 256 : 320;  // block threads
    constexpr int TC    = (LAYER == 0) ? 64 : 144;
    constexpr int TSTR  = (LAYER == 0) ? 64 : 168;   // padded T stride (8 mod 32)
    constexpr int TW    = (LAYER == 0) ? 512 : (LAYER == 1 ? 896 : 128);
    constexpr int NOUT  = (LAYER == 2) ? 8 : 48;
    constexpr int MSTRE = (LAYER == 0) ? 68 : 148;   // padded M stride, 16B-aligned

    // ---- shared layout (floats) ----
    constexpr int oT   = 0;                               // NS*TSTR
    constexpr int oF0  = oT + NS * TSTR;                  // 24*16
    constexpr int oF1  = oF0 + NS * 16;                   // 24*24 (f1T: [i2*8+u])
    constexpr int oY   = oF1 + ((LAYER == 0) ? 0 : NS * 24); // 24*8
    constexpr int oBas = oY + NS * 8;                     // 24*10
    constexpr int oH   = oBas + NS * NBASIS;              // 24*32
    constexpr int SM0  = oH + NS * HHID;
    constexpr int oU   = 32 * MSTRE;
    constexpr int SMe  = oU + NOUT * 33;
    constexpr int SM   = (SM0 > SMe) ? SM0 : SMe;
    __shared__ float sm[SM];

    const int tid  = threadIdx.x;
    const int blk  = blockIdx.x;
    const int sp   = blk & (SPLIT - 1);
    const int atom = blk >> 3;           // z*NN + a
    const int z    = atom / NN, a = atom % NN;
    const int nb0  = sp * NS;

    // ---------------- P0: stage activated features; basis + Y --------------
    if constexpr (LAYER == 0) {
        for (int i = tid; i < NS * 16; i += NT)
            sm[oF0 + i] = fin0[(z * NN + nb0) * 16 + i] * S_SCALE;
    } else {
        for (int i = tid; i < NS * 16; i += NT)
            sm[oF0 + i] = fin0[(z * NN + nb0) * 16 + i];
        for (int i = tid; i < NS * 24; i += NT)
            sm[oF1 + i] = fin1[(z * NN + nb0) * 24 + i];
    }
    {
        const float ax = geo[(z * NN + a) * 3 + 0];
        const float ay = geo[(z * NN + a) * 3 + 1];
        const float az = geo[(z * NN + a) * 3 + 2];
        for (int idx = tid; idx < NS * 12; idx += NT) {
            int bl = idx / 12, it = idx - bl * 12;
            const float* gb = &geo[(z * NN + nb0 + bl) * 3];
            float rx = ax - gb[0], ry = ay - gb[1], rz = az - gb[2];
            float r = sqrtf(rx * rx + ry * ry + rz * rz + 1e-12f);
            if (it < NBASIS) {
                float dg = r * 2.25f - (float)it;    // step = 4/9
                float bas = 0.0f;
                if (fabsf(dg) < 1.0f) {
                    float cc = cosf(1.5707963267948966f * dg);
                    bas = cc * cc;
                }
                sm[oBas + bl * NBASIS + it] = bas;
            } else {
                float inv = 1.0f / fmaxf(r, 1e-6f);
                float ux = rx * inv, uy = ry * inv, uz = rz * inv;
                if (it == 10) {
                    sm[oY + bl * 8 + 0] = 0.4886025119029199f * uy;
                    sm[oY + bl * 8 + 1] = 0.4886025119029199f * uz;
                    sm[oY + bl * 8 + 2] = 0.4886025119029199f * ux;
                } else {
                    sm[oY + bl * 8 + 3] = 1.0925484305920792f * ux * uy;
                    sm[oY + bl * 8 + 4] = 1.0925484305920792f * uy * uz;
                    sm[oY + bl * 8 + 5] = 0.31539156525252005f * (2.0f * uz * uz - ux * ux - uy * uy);
                    sm[oY + bl * 8 + 6] = 1.0925484305920792f * ux * uz;
                    sm[oY + bl * 8 + 7] = 0.5462742152960396f * (ux * ux - uy * uy);
                }
            }
        }
    }
    __syncthreads();

    // ---------------- P1: radial hidden h ----------------------------------
    for (int idx = tid; idx < NS * 32; idx += NT) {
        int bl = idx >> 5, j = idx & 31;
        float su = 0.0f;
#pragma unroll
        for (int k = 0; k < NBASIS; ++k)
            su += sm[oBas + bl * NBASIS + k] * w0g[k * HHID + j];
        sm[oH + idx] = relu_r(su * ISQ10 + b0g[j]);
    }
    __syncthreads();

    // ---------------- P2: T columns, region-split ---------------------------
    if constexpr (LAYER == 0) {
        for (int idx = tid; idx < NS * 16; idx += NT) {
            int loc = idx >> 4, c = idx & 15;
            sm[oT + loc * TSTR + c] = 0.28209479177387814f * sm[oF0 + loc * 16 + c];
        }
#pragma unroll
        for (int i2 = 0; i2 < 3; ++i2)
            for (int idx = tid; idx < NS * 16; idx += NT) {
                int loc = idx >> 4, v = idx & 15;
                sm[oT + loc * TSTR + 16 + i2 * 16 + v] =
                    sm[oY + loc * 8 + i2] * sm[oF0 + loc * 16 + v] * 0.5773502691896258f;
            }
    } else {
        for (int idx = tid; idx < NS * 16; idx += NT) {
            int loc = idx >> 4, c = idx & 15;
            sm[oT + loc * TSTR + c] = 0.28209479177387814f * sm[oF0 + loc * 16 + c];
        }
        for (int idx = tid; idx < NS * 8; idx += NT) {
            int loc = idx >> 3, u = idx & 7;
            const float* Yb = &sm[oY + loc * 8];
            const float* fT = &sm[oF1 + loc * 24];
            sm[oT + loc * TSTR + 16 + u] =
                (fT[u] * Yb[0] + fT[8 + u] * Yb[1] + fT[16 + u] * Yb[2]) * 0.5773502691896258f;
        }
#pragma unroll
        for (int i2 = 0; i2 < 3; ++i2)
            for (int idx = tid; idx < NS * 16; idx += NT) {
                int loc = idx >> 4, v = idx & 15;
                sm[oT + loc * TSTR + 24 + i2 * 16 + v] =
                    sm[oY + loc * 8 + i2] * sm[oF0 + loc * 16 + v] * 0.5773502691896258f;
            }
        for (int idx = tid; idx < NS * 24; idx += NT) {
            int loc = idx / 24, j = idx - loc * 24;
            sm[oT + loc * TSTR + 72 + j] =
                sm[oF1 + loc * 24 + j] * (0.28209479177387814f * 0.5773502691896258f);
        }
#pragma unroll
        for (int i2 = 0; i2 < 3; ++i2) {
            const int i1 = (i2 + 1) % 3, i3 = (i2 + 2) % 3;
            for (int idx = tid; idx < NS * 8; idx += NT) {
                int loc = idx >> 3, u = idx & 7;
                const float* Yb = &sm[oY + loc * 8];
                const float* fT = &sm[oF1 + loc * 24];
                sm[oT + loc * TSTR + 96 + i2 * 8 + u] =
                    (fT[i1 * 8 + u] * Yb[i3] - fT[i3 * 8 + u] * Yb[i1]) * 0.4082482904638631f;
            }
        }
#pragma unroll
        for (int i2 = 0; i2 < 3; ++i2)
            for (int idx = tid; idx < NS * 8; idx += NT) {
                int loc = idx >> 3, u = idx & 7;
                const float* Yb = &sm[oY + loc * 8];
                const float* fT = &sm[oF1 + loc * 24];
                const float D  = 0.31622776601683794f;
                const float Bc = 0.18257418583505536f;
                float f0v = fT[u], f1v = fT[8 + u], f2v = fT[16 + u];
                float Y20 = Yb[3], Y21 = Yb[4], Y22 = Yb[5], Y23 = Yb[6], Y24 = Yb[7];
                float val;
                if (i2 == 0)      val = D * (Y20 * f2v + Y21 * f1v) - (Bc * Y22 + D * Y24) * f0v;
                else if (i2 == 1) val = D * (Y21 * f0v + Y23 * f2v) + 2.0f * Bc * Y22 * f1v;
                else              val = D * (Y20 * f0v + Y23 * f1v + Y24 * f2v) - Bc * Y22 * f2v;
                sm[oT + loc * TSTR + 120 + i2 * 8 + u] = val;
            }
    }
    __syncthreads();

    // ---------------- P3: M update, register-tiled (single pass) ------------
    if constexpr (LAYER == 0) {
        const int hr = tid >> 4, cg = tid & 15;     // 16 row-groups x 16 col-groups
        float acc[2][4];
#pragma unroll
        for (int rr = 0; rr < 2; ++rr)
#pragma unroll
            for (int cc = 0; cc < 4; ++cc) acc[rr][cc] = 0.0f;
#pragma unroll 4
        for (int bl = 0; bl < NS; ++bl) {
            float2 hv = *(const float2*)&sm[oH + bl * 32 + hr * 2];
            float4 tv = *(const float4*)&sm[oT + bl * 64 + cg * 4];
            float hvv[2] = {hv.x, hv.y};
            float tvv[4] = {tv.x, tv.y, tv.z, tv.w};
#pragma unroll
            for (int rr = 0; rr < 2; ++rr)
#pragma unroll
                for (int cc = 0; cc < 4; ++cc) acc[rr][cc] += hvv[rr] * tvv[cc];
        }
        __syncthreads();   // all T/h reads done before M overwrites region
#pragma unroll
        for (int rr = 0; rr < 2; ++rr)
#pragma unroll
            for (int cc = 0; cc < 4; ++cc)
                sm[(hr * 2 + rr) * MSTRE + cg * 4 + cc] = acc[rr][cc];
    } else {
        const int hr = tid / 40;                    // 0..7  (8 row-groups of 4)
        const int cg = tid - hr * 40;               // 0..39 (40 col-groups of 4)
        float acc[4][4];
#pragma unroll
        for (int rr = 0; rr < 4; ++rr)
#pragma unroll
            for (int cc = 0; cc < 4; ++cc) acc[rr][cc] = 0.0f;
#pragma unroll 4
        for (int bl = 0; bl < NS; ++bl) {
            float4 hv = *(const float4*)&sm[oH + bl * 32 + hr * 4];
            float4 tv = *(const float4*)&sm[oT + bl * TSTR + cg * 4];  // aligned b128
            float hvv[4] = {hv.x, hv.y, hv.z, hv.w};
            float tvv[4] = {tv.x, tv.y, tv.z, tv.w};
#pragma unroll
            for (int rr = 0; rr < 4; ++rr)
#pragma unroll
                for (int cc = 0; cc < 4; ++cc) acc[rr][cc] += hvv[rr] * tvv[cc];
        }
        __syncthreads();   // all T/h reads done before M overwrites region
        if (cg < 36) {     // cols cg*4..cg*4+3 < 144
#pragma unroll
            for (int rr = 0; rr < 4; ++rr)
#pragma unroll
                for (int cc = 0; cc < 4; ++cc)
                    sm[(hr * 4 + rr) * MSTRE + cg * 4 + cc] = acc[rr][cc];
        }
    }
    __syncthreads();

    // ---------------- P4: epilogue, float4-vectorized -----------------------
    constexpr int NITEM = NOUT * 32;
    for (int idx = tid; idx < NITEM; idx += NT) {
        int h = idx / NOUT, o = idx - h * NOUT;
        const float* wr = &wout[h * TW];
        const float* mr = &sm[h * MSTRE];
        float U;
        if constexpr (LAYER == 0) {
            const float sc = I32 * 0.25f;
            float accv;
            if (o < 24) {
                const float4* w4 = (const float4*)(wr + o * 16);
                const float4* m4 = (const float4*)(mr);
                accv = dot4(w4[0], m4[0]) + dot4(w4[1], m4[1])
                     + dot4(w4[2], m4[2]) + dot4(w4[3], m4[3]);
            } else {
                int j = o - 24, u = j & 7, i2 = j >> 3;
                const float4* w4 = (const float4*)(wr + 384 + u * 16);
                const float4* m4 = (const float4*)(mr + 16 + i2 * 16);
                accv = dot4(w4[0], m4[0]) + dot4(w4[1], m4[1])
                     + dot4(w4[2], m4[2]) + dot4(w4[3], m4[3]);
            }
            U = accv * sc;
        } else if constexpr (LAYER == 1) {
            float aA, aB;
            if (o < 24) {
                const float4* w4 = (const float4*)(wr + o * 16);
                const float4* m4 = (const float4*)(mr);
                aA = dot4(w4[0], m4[0]) + dot4(w4[1], m4[1])
                   + dot4(w4[2], m4[2]) + dot4(w4[3], m4[3]);
                const float4* w8 = (const float4*)(wr + 384 + o * 8);
                const float4* m8 = (const float4*)(mr + 16);
                aB = dot4(w8[0], m8[0]) + dot4(w8[1], m8[1]);
                U = (aA * I32 + aB * 0.25f) * I32;
            } else {
                int j = o - 24, u = j & 7, i2 = j >> 3;
                const float4* w4 = (const float4*)(wr + 576 + u * 16);
                const float4* m4 = (const float4*)(mr + 24 + i2 * 16);
                aA = dot4(w4[0], m4[0]) + dot4(w4[1], m4[1])
                   + dot4(w4[2], m4[2]) + dot4(w4[3], m4[3]);
                const float4* wB0 = (const float4*)(wr + 704 + u * 8);
                const float4* wB1 = (const float4*)(wr + 768 + u * 8);
                const float4* wB2 = (const float4*)(wr + 832 + u * 8);
                const float4* mB0 = (const float4*)(mr + 72 + i2 * 8);
                const float4* mB1 = (const float4*)(mr + 96 + i2 * 8);
                const float4* mB2 = (const float4*)(mr + 120 + i2 * 8);
                aB = dot4(wB0[0], mB0[0]) + dot4(wB0[1], mB0[1])
                   + dot4(wB1[0], mB1[0]) + dot4(wB1[1], mB1[1])
                   + dot4(wB2[0], mB2[0]) + dot4(wB2[1], mB2[1]);
                U = (aA * 0.125f + aB * I32) * I32;
            }
        } else {  // LAYER == 2
            float aA, aB;
            if (o < 2) {
                const float4* w4 = (const float4*)(wr + o * 16);
                const float4* m4 = (const float4*)(mr);
                aA = dot4(w4[0], m4[0]) + dot4(w4[1], m4[1])
                   + dot4(w4[2], m4[2]) + dot4(w4[3], m4[3]);
                const float4* w8 = (const float4*)(wr + 32 + o * 8);
                const float4* m8 = (const float4*)(mr + 16);
                aB = dot4(w8[0], m8[0]) + dot4(w8[1], m8[1]);
                U = (aA * I32 + aB * 0.25f) * I32;
            } else {
                int j = o - 2, u = j & 1, i2 = j >> 1;
                const float4* w4 = (const float4*)(wr + 48 + u * 16);
                const float4* m4 = (const float4*)(mr + 24 + i2 * 16);
                aA = dot4(w4[0], m4[0]) + dot4(w4[1], m4[1])
                   + dot4(w4[2], m4[2]) + dot4(w4[3], m4[3]);
                const float4* wB0 = (const float4*)(wr + 80 + u * 8);
                const float4* wB1 = (const float4*)(wr + 96 + u * 8);
                const float4* wB2 = (const float4*)(wr + 112 + u * 8);
                const float4* mB0 = (const float4*)(mr + 72 + i2 * 8);
                const float4* mB1 = (const float4*)(mr + 96 + i2 * 8);
                const float4* mB2 = (const float4*)(mr + 120 + i2 * 8);
                aB = dot4(wB0[0], mB0[0]) + dot4(wB0[1], mB0[1])
                   + dot4(wB1[0], mB1[0]) + dot4(wB1[1], mB1[1])
                   + dot4(wB2[0], mB2[0]) + dot4(wB2[1], mB2[1]);
                U = (aA * 0.125f + aB * I32) * I32;
            }
        }
        sm[oU + o * 33 + h] = U;
    }
    __syncthreads();

    if (tid < NOUT) {
        float su = 0.0f;
#pragma unroll
        for (int h = 0; h < 32; ++h) su += sm[oU + tid * 33 + h];
        part[blk * NOUT + tid] = su;
    }
}

// ---------------------------------------------------------------------------
// Final sum: out[atom][2*4] interleaved from 8 split partials of layer 2.
// ---------------------------------------------------------------------------
__global__ __launch_bounds__(256) void tfn_fin(
    const float* __restrict__ part2, float* __restrict__ out)
{
    int t = blockIdx.x * 256 + threadIdx.x;  // < BB*NN*8
    int atom = t >> 3, o = t & 7;
    const float* p = &part2[atom * SPLIT * 8];
    float su = ((p[o] + p[8 + o]) + (p[16 + o] + p[24 + o]))
             + ((p[32 + o] + p[40 + o]) + (p[48 + o] + p[56 + o]));
    int pos;
    if (o < 2) pos = o * 4;
    else { int j = o - 2; int i2 = j >> 1, u = j & 1; pos = u * 4 + 1 + i2; }
    out[atom * 8 + pos] = su;
}

// ---------------------------------------------------------------------------
// Fallback: verified round-1 monolithic kernel (used only if ws too small).
// ---------------------------------------------------------------------------
template <int LAYER>
__global__ __launch_bounds__(256) void tfn_layer_mono(
    const float* __restrict__ geo,
    const float* __restrict__ fin0,
    const float* __restrict__ fin1,
    const float* __restrict__ w0,
    const float* __restrict__ b0g,
    const float* __restrict__ wout,
    float* __restrict__ o0,
    float* __restrict__ o1)
{
    constexpr int TC   = (LAYER == 0) ? 64 : 144;
    constexpr int TW   = (LAYER == 0) ? 512 : (LAYER == 1 ? 896 : 128);
    constexpr int CPT  = TC / 8;
    constexpr int CPTT = TC / 16;

    const int tid = threadIdx.x;
    const int blk = blockIdx.x;
    const int z = blk / NN, a = blk % NN;

    __shared__ float geoL[NN * 3];
    __shared__ float f0L[NN * 16];
    __shared__ float f1L[(LAYER == 0) ? 1 : (NN * 24)];
    __shared__ float w0L[NBASIS * HHID];
    __shared__ float b0L[HHID];
    __shared__ float YC[16 * 8];
    __shared__ float basC[16 * NBASIS];
    __shared__ float hC[16 * HHID];
    __shared__ float tC[16 * TC];
    __shared__ float Mlds[HHID * TC];
    __shared__ float outS[32];

    const float s = S_SCALE;

    for (int i = tid; i < NN * 3; i += 256) geoL[i] = geo[z * NN * 3 + i];
    for (int i = tid; i < NN * 16; i += 256) {
        float v = fin0[z * NN * 16 + i];
        if (LAYER == 0) v *= s;
        f0L[i] = v;
    }
    if constexpr (LAYER != 0) {
        for (int i = tid; i < NN * 24; i += 256) f1L[i] = fin1[z * NN * 24 + i];
    }
    for (int i = tid; i < NBASIS * HHID; i += 256) w0L[i] = w0[i];
    if (tid < HHID) b0L[tid] = b0g[tid];
    __syncthreads();

    const float ax = geoL[a * 3 + 0], ay = geoL[a * 3 + 1], az = geoL[a * 3 + 2];

    float Macc[CPT];
#pragma unroll
    for (int j = 0; j < CPT; ++j) Macc[j] = 0.0f;
    const int hh  = tid >> 3;
    const int cg0 = (tid & 7) * CPT;

    for (int cb = 0; cb < NN / 16; ++cb) {
        {
            const int bl = tid & 15, item = tid >> 4;
            const int b = cb * 16 + bl;
            float rx = ax - geoL[b * 3 + 0];
            float ry = ay - geoL[b * 3 + 1];
            float rz = az - geoL[b * 3 + 2];
            float r = sqrtf(rx * rx + ry * ry + rz * rz + 1e-12f);
            float inv = 1.0f / fmaxf(r, 1e-6f);
            float ux = rx * inv, uy = ry * inv, uz = rz * inv;
            if (item < NBASIS) {
                float dg = r * 2.25f - (float)item;
                float bas = 0.0f;
                if (fabsf(dg) < 1.0f) {
                    float cc = cosf(1.5707963267948966f * dg);
                    bas = cc * cc;
                }
                basC[bl * NBASIS + item] = bas;
            } else if (item == 10) {
                YC[bl * 8 + 0] = 0.4886025119029199f * uy;
                YC[bl * 8 + 1] = 0.4886025119029199f * uz;
                YC[bl * 8 + 2] = 0.4886025119029199f * ux;
            } else if (item == 11) {
                YC[bl * 8 + 3] = 1.0925484305920792f * ux * uy;
                YC[bl * 8 + 4] = 1.0925484305920792f * uy * uz;
                YC[bl * 8 + 5] = 0.31539156525252005f * (2.0f * uz * uz - ux * ux - uy * uy);
                YC[bl * 8 + 6] = 1.0925484305920792f * ux * uz;
                YC[bl * 8 + 7] = 0.5462742152960396f * (ux * ux - uy * uy);
            }
        }
        __syncthreads();

#pragma unroll
        for (int rep = 0; rep < 2; ++rep) {
            int idx = tid + rep * 256;
            int bl = idx >> 5, h2 = idx & 31;
            float su = 0.0f;
#pragma unroll
            for (int k = 0; k < NBASIS; ++k) su += basC[bl * NBASIS + k] * w0L[k * HHID + h2];
            hC[bl * HHID + h2] = relu_r(su * ISQ10 + b0L[h2]);
        }

        {
            const int bl = tid >> 4, cg = tid & 15;
            const int b = cb * 16 + bl;
            const float* Yb = &YC[bl * 8];
#pragma unroll
            for (int jj = 0; jj < CPTT; ++jj) {
                int c = cg * CPTT + jj;
                float val;
                if constexpr (LAYER == 0) {
                    if (c < 16) {
                        val = 0.28209479177387814f * f0L[b * 16 + c];
                    } else {
                        int q = c - 16, v = q / 3, i2 = q % 3;
                        val = Yb[i2] * f0L[b * 16 + v] * 0.5773502691896258f;
                    }
                } else {
                    if (c < 16) {
                        val = 0.28209479177387814f * f0L[b * 16 + c];
                    } else if (c < 24) {
                        int v = c - 16;
                        const float* f = &f1L[(b * 8 + v) * 3];
                        val = (f[0] * Yb[0] + f[1] * Yb[1] + f[2] * Yb[2]) * 0.5773502691896258f;
                    } else if (c < 72) {
                        int q = c - 24, v = q / 3, i2 = q % 3;
                        val = Yb[i2] * f0L[b * 16 + v] * 0.5773502691896258f;
                    } else if (c < 96) {
                        int q = c - 72, v = q / 3, i2 = q % 3;
                        val = f1L[(b * 8 + v) * 3 + i2] * (0.28209479177387814f * 0.5773502691896258f);
                    } else if (c < 120) {
                        int q = c - 96, v = q / 3, i2 = q % 3;
                        const float* f = &f1L[(b * 8 + v) * 3];
                        int i1 = (i2 + 1) % 3, i3 = (i2 + 2) % 3;
                        val = (f[i1] * Yb[i3] - f[i3] * Yb[i1]) * 0.4082482904638631f;
                    } else {
                        int q = c - 120, v = q / 3, i2 = q % 3;
                        const float* f = &f1L[(b * 8 + v) * 3];
                        const float D = 0.31622776601683794f;
                        const float Bc = 0.18257418583505536f;
                        float Y20 = Yb[3], Y21 = Yb[4], Y22 = Yb[5], Y23 = Yb[6], Y24 = Yb[7];
                        if (i2 == 0)      val = D * (Y20 * f[2] + Y21 * f[1]) - (Bc * Y22 + D * Y24) * f[0];
                        else if (i2 == 1) val = D * (Y21 * f[0] + Y23 * f[2]) + 2.0f * Bc * Y22 * f[1];
                        else              val = D * (Y20 * f[0] + Y23 * f[1] + Y24 * f[2]) - Bc * Y22 * f[2];
                    }
                }
                tC[bl * TC + c] = val;
            }
        }
        __syncthreads();

#pragma unroll 4
        for (int bl = 0; bl < 16; ++bl) {
            float hv = hC[bl * HHID + hh];
#pragma unroll
            for (int j = 0; j < CPT; ++j) Macc[j] += hv * tC[bl * TC + cg0 + j];
        }
        __syncthreads();
    }

#pragma unroll
    for (int j = 0; j < CPT; ++j) Mlds[hh * TC + cg0 + j] = Macc[j];
    __syncthreads();

    const float i32 = I32;

    if constexpr (LAYER == 0) {
        const float sc = i32 * 0.25f;
        float o1v = 0.0f;
        if (tid < 24) {
            float acc = 0.0f;
            for (int h2 = 0; h2 < 32; ++h2) {
                const float* wr = &wout[h2 * TW + tid * 16];
                const float* mr = &Mlds[h2 * TC];
#pragma unroll
                for (int v = 0; v < 16; ++v) acc += wr[v] * mr[v];
            }
            outS[tid] = acc * sc;
        } else if (tid >= 32 && tid < 56) {
            int idx = tid - 32, u = idx / 3, i2 = idx % 3;
            float acc = 0.0f;
            for (int h2 = 0; h2 < 32; ++h2) {
                const float* wr = &wout[h2 * TW + 384 + u * 16];
                const float* mr = &Mlds[h2 * TC + 16 + i2];
#pragma unroll
                for (int v = 0; v < 16; ++v) acc += wr[v] * mr[v * 3];
            }
            o1v = acc * sc;
        }
        __syncthreads();
        if (tid < 16) {
            o0[(z * NN + a) * 16 + tid] = relu_r(outS[tid]) * s;
        } else if (tid >= 32 && tid < 56) {
            int idx = tid - 32, u = idx / 3, i2 = idx % 3;
            float g = sigmoid_r(outS[16 + u]);
            o1[((z * NN + a) * 8 + u) * 3 + i2] = o1v * g * s;
        }
    } else if constexpr (LAYER == 1) {
        float o1v = 0.0f;
        if (tid < 24) {
            float aA = 0.0f, aB = 0.0f;
            for (int h2 = 0; h2 < 32; ++h2) {
                const float* wr = &wout[h2 * TW];
                const float* mr = &Mlds[h2 * TC];
#pragma unroll
                for (int v = 0; v < 16; ++v) aA += wr[tid * 16 + v] * mr[v];
#pragma unroll
                for (int v = 0; v < 8; ++v) aB += wr[384 + tid * 8 + v] * mr[16 + v];
            }
            outS[tid] = (aA * i32 + aB * 0.25f) * i32;
        } else if (tid >= 32 && tid < 56) {
            int idx = tid - 32, u = idx / 3, i2 = idx % 3;
            float aA = 0.0f, aB = 0.0f;
            for (int h2 = 0; h2 < 32; ++h2) {
                const float* wr = &wout[h2 * TW];
                const float* mr = &Mlds[h2 * TC];
#pragma unroll
                for (int v = 0; v < 16; ++v) aA += wr[576 + u * 16 + v] * mr[24 + v * 3 + i2];
#pragma unroll
                for (int v = 0; v < 8; ++v)
                    aB += wr[704 + u * 8 + v] * mr[72 + v * 3 + i2]
                        + wr[768 + u * 8 + v] * mr[96 + v * 3 + i2]
                        + wr[832 + u * 8 + v] * mr[120 + v * 3 + i2];
            }
            o1v = (aA * 0.125f + aB * i32) * i32;
        }
        __syncthreads();
        if (tid < 16) {
            o0[(z * NN + a) * 16 + tid] = relu_r(outS[tid]) * s;
        } else if (tid >= 32 && tid < 56) {
            int idx = tid - 32, u = idx / 3, i2 = idx % 3;
            float g = sigmoid_r(outS[16 + u]);
            o1[((z * NN + a) * 8 + u) * 3 + i2] = o1v * g * s;
        }
    } else {
        if (tid < 2) {
            float aA = 0.0f, aB = 0.0f;
            for (int h2 = 0; h2 < 32; ++h2) {
                const float* wr = &wout[h2 * TW];
                const float* mr = &Mlds[h2 * TC];
#pragma unroll
                for (int v = 0; v < 16; ++v) aA += wr[tid * 16 + v] * mr[v];
#pragma unroll
                for (int v = 0; v < 8; ++v) aB += wr[32 + tid * 8 + v] * mr[16 + v];
            }
            o0[(z * NN + a) * 8 + tid * 4] = (aA * i32 + aB * 0.25f) * i32;
        } else if (tid >= 32 && tid < 38) {
            int idx = tid - 32, u = idx / 3, i2 = idx % 3;
            float aA = 0.0f, aB = 0.0f;
            for (int h2 = 0; h2 < 32; ++h2) {
                const float* wr = &wout[h2 * TW];
                const float* mr = &Mlds[h2 * TC];
#pragma unroll
                for (int v = 0; v < 16; ++v) aA += wr[48 + u * 16 + v] * mr[24 + v * 3 + i2];
#pragma unroll
                for (int v = 0; v < 8; ++v)
                    aB += wr[80 + u * 8 + v] * mr[72 + v * 3 + i2]
                        + wr[96 + u * 8 + v] * mr[96 + v * 3 + i2]
                        + wr[112 + u * 8 + v] * mr[120 + v * 3 + i2];
            }
            o0[(z * NN + a) * 8 + u * 4 + 1 + i2] = (aA * 0.125f + aB * i32) * i32;
        }
    }
}

extern "C" void kernel_launch(void* const* d_in, const int* in_sizes, int n_in,
                              void* d_out, int out_size, void* d_ws, size_t ws_size,
                              hipStream_t stream) {
    const float* features = (const float*)d_in[0];
    const float* geometry = (const float*)d_in[1];
    const float* c0w0   = (const float*)d_in[2];
    const float* c0b0   = (const float*)d_in[3];
    const float* c0wout = (const float*)d_in[4];
    const float* c1w0   = (const float*)d_in[5];
    const float* c1b0   = (const float*)d_in[6];
    const float* c1wout = (const float*)d_in[7];
    const float* c2w0   = (const float*)d_in[8];
    const float* c2b0   = (const float*)d_in[9];
    const float* c2wout = (const float*)d_in[10];
    float* out = (float*)d_out;

    float* ws = (float*)d_ws;
    const size_t NBLK  = (size_t)BB * NN * SPLIT;                // 3072
    const size_t NATOM = (size_t)BB * NN;                        // 384
    const size_t need  = NBLK * 48 * 2 + NBLK * 8 + NATOM * 40 * 2;

    if (ws_size >= need * sizeof(float)) {
        float* partA = ws;
        float* partB = partA + NBLK * 48;
        float* part2 = partB + NBLK * 48;
        float* fa0A  = part2 + NBLK * 8;
        float* fa1A  = fa0A + NATOM * 16;
        float* fa0B  = fa1A + NATOM * 24;
        float* fa1B  = fa0B + NATOM * 16;

        dim3 g1((unsigned)NBLK), blk256(256), blk320(320);
        dim3 gact((unsigned)((NATOM * 40 + 255) / 256));
        hipLaunchKernelGGL((tfn_s1<0>), g1, blk256, 0, stream,
                           features, nullptr, geometry, c0w0, c0b0, c0wout, partA);
        hipLaunchKernelGGL(tfn_act, gact, blk256, 0, stream, partA, fa0A, fa1A);
        hipLaunchKernelGGL((tfn_s1<1>), g1, blk320, 0, stream,
                           fa0A, fa1A, geometry, c1w0, c1b0, c1wout, partB);
        hipLaunchKernelGGL(tfn_act, gact, blk256, 0, stream, partB, fa0B, fa1B);
        hipLaunchKernelGGL((tfn_s1<2>), g1, blk320, 0, stream,
                           fa0B, fa1B, geometry, c2w0, c2b0, c2wout, part2);
        hipLaunchKernelGGL(tfn_fin, dim3(BB * NN * 8 / 256), blk256, 0, stream,
                           part2, out);
    } else {
        float* f0a = ws;
        float* f1a = f0a + BB * NN * 16;
        float* f0b = f1a + BB * NN * 24;
        float* f1b = f0b + BB * NN * 16;
        dim3 grid(BB * NN), blk(256);
        hipLaunchKernelGGL((tfn_layer_mono<0>), grid, blk, 0, stream,
                           geometry, features, nullptr, c0w0, c0b0, c0wout, f0a, f1a);
        hipLaunchKernelGGL((tfn_layer_mono<1>), grid, blk, 0, stream,
                           geometry, f0a, f1a, c1w0, c1b0, c1wout, f0b, f1b);
        hipLaunchKernelGGL((tfn_layer_mono<2>), grid, blk, 0, stream,
                           geometry, f0b, f1b, c2w0, c2b0, c2wout, out, nullptr);
    }
}

// Round 12
// 110.734 us; speedup vs baseline: 1.1644x; 1.1644x over previous
//
#include <hip/hip_runtime.h>
#include <math.h>

// Tensor-field-network decoder: B=2, N=192, 3 conv layers (2 gated + 1 final).
// Round-12: revert to round-10 (best: 114.3us) + merge P1|P2 into one phase
// (they are independent: P1 writes h from bas; P2 writes T from f0/f1/Y; both
// read only P0 outputs; P3 reads both) -> 5 barriers instead of 6 and a wider
// independent-instruction window. r11's aligned-cg*4 mapping reverted: cg*5
// (coprime to 32 banks) was conflict-free; cg*4 was 5-way conflicted.
// Fallback to verified round-1 monolithic kernels if ws too small.

#define NN 192
#define BB 2
#define SPLIT 8
#define NS 24
#define NBASIS 10
#define HHID 32

__device__ __forceinline__ float relu_r(float x) {
    return fmaxf(x, 0.0f) * 1.4142135623730951f;
}
__device__ __forceinline__ float sigmoid_r(float x) {
    return (1.0f / (1.0f + expf(-x))) * 1.84623f;
}
__device__ __forceinline__ float dot4(float4 a, float4 b) {
    return a.x * b.x + a.y * b.y + a.z * b.z + a.w * b.w;
}

#define S_SCALE 0.07216878364870323f   // 1/sqrt(192)
#define ISQ10   0.31622776601683794f   // 1/sqrt(10)
#define I32     0.1767766952966369f    // 1/sqrt(32)

// ---------------------------------------------------------------------------
// tfn_act: per-atom sum of 8 split partials + activation + gating + scale.
// ---------------------------------------------------------------------------
__global__ __launch_bounds__(256) void tfn_act(
    const float* __restrict__ part, float* __restrict__ fa0, float* __restrict__ fa1)
{
    int t = blockIdx.x * 256 + threadIdx.x;     // < B*N*40
    if (t >= BB * NN * 40) return;
    int atom = t / 40, c = t - atom * 40;
    const float* p = &part[atom * SPLIT * 48];
    if (c < 16) {
        float s = 0.0f;
#pragma unroll
        for (int sp = 0; sp < SPLIT; ++sp) s += p[sp * 48 + c];
        fa0[atom * 16 + c] = relu_r(s) * S_SCALE;
    } else {
        int j = c - 16, u = j & 7;
        float g = 0.0f, v = 0.0f;
#pragma unroll
        for (int sp = 0; sp < SPLIT; ++sp) {
            g += p[sp * 48 + 16 + u];
            v += p[sp * 48 + 24 + j];
        }
        fa1[atom * 24 + j] = v * sigmoid_r(g) * S_SCALE;
    }
}

template <int LAYER>
__global__ __launch_bounds__(256, 4) void tfn_s1(
    const float* __restrict__ fin0,  // L0: features [B,N,16]; L1/2: fa0 [B*N,16]
    const float* __restrict__ fin1,  // L1/2: fa1 [B*N,24]
    const float* __restrict__ geo,   // [B,N,3]
    const float* __restrict__ w0g,   // [10,32]
    const float* __restrict__ b0g,   // [32]
    const float* __restrict__ wout,  // [32, TW]
    float* __restrict__ part)        // [B*N*SPLIT, NOUT]
{
    constexpr int TC    = (LAYER == 0) ? 64 : 144;
    constexpr int TSTR  = (LAYER == 0) ? 64 : 168;   // padded T stride (8 mod 32)
    constexpr int TW    = (LAYER == 0) ? 512 : (LAYER == 1 ? 896 : 128);
    constexpr int NOUT  = (LAYER == 2) ? 8 : 48;
    constexpr int MSTRE = (LAYER == 0) ? 68 : 148;   // padded M stride, 16B-aligned
    constexpr int R     = (LAYER == 0) ? 2 : 4;      // h-rows per thread
    constexpr int C     = (LAYER == 0) ? 4 : 5;      // cols per thread

    // ---- shared layout (floats) ----
    constexpr int oT   = 0;                               // NS*TSTR
    constexpr int oF0  = oT + NS * TSTR;                  // 24*16
    constexpr int oF1  = oF0 + NS * 16;                   // 24*24 (f1T: [i2*8+u])
    constexpr int oY   = oF1 + ((LAYER == 0) ? 0 : NS * 24); // 24*8
    constexpr int oBas = oY + NS * 8;                     // 24*10
    constexpr int oH   = oBas + NS * NBASIS;              // 24*32
    constexpr int SM0  = oH + NS * HHID;
    constexpr int oU   = 32 * MSTRE;
    constexpr int SMe  = oU + NOUT * 33;
    constexpr int SM   = (SM0 > SMe) ? SM0 : SMe;
    __shared__ float sm[SM];

    const int tid  = threadIdx.x;
    const int blk  = blockIdx.x;
    const int sp   = blk & (SPLIT - 1);
    const int atom = blk >> 3;           // z*NN + a
    const int z    = atom / NN, a = atom % NN;
    const int nb0  = sp * NS;

    // ---------------- P0: stage activated features; basis + Y --------------
    if constexpr (LAYER == 0) {
        for (int i = tid; i < NS * 16; i += 256)
            sm[oF0 + i] = fin0[(z * NN + nb0) * 16 + i] * S_SCALE;
    } else {
        for (int i = tid; i < NS * 16; i += 256)
            sm[oF0 + i] = fin0[(z * NN + nb0) * 16 + i];
        for (int i = tid; i < NS * 24; i += 256)
            sm[oF1 + i] = fin1[(z * NN + nb0) * 24 + i];
    }
    {
        const float ax = geo[(z * NN + a) * 3 + 0];
        const float ay = geo[(z * NN + a) * 3 + 1];
        const float az = geo[(z * NN + a) * 3 + 2];
        for (int idx = tid; idx < NS * 12; idx += 256) {
            int bl = idx / 12, it = idx - bl * 12;
            const float* gb = &geo[(z * NN + nb0 + bl) * 3];
            float rx = ax - gb[0], ry = ay - gb[1], rz = az - gb[2];
            float r = sqrtf(rx * rx + ry * ry + rz * rz + 1e-12f);
            if (it < NBASIS) {
                float dg = r * 2.25f - (float)it;    // step = 4/9
                float bas = 0.0f;
                if (fabsf(dg) < 1.0f) {
                    float cc = cosf(1.5707963267948966f * dg);
                    bas = cc * cc;
                }
                sm[oBas + bl * NBASIS + it] = bas;
            } else {
                float inv = 1.0f / fmaxf(r, 1e-6f);
                float ux = rx * inv, uy = ry * inv, uz = rz * inv;
                if (it == 10) {
                    sm[oY + bl * 8 + 0] = 0.4886025119029199f * uy;
                    sm[oY + bl * 8 + 1] = 0.4886025119029199f * uz;
                    sm[oY + bl * 8 + 2] = 0.4886025119029199f * ux;
                } else {
                    sm[oY + bl * 8 + 3] = 1.0925484305920792f * ux * uy;
                    sm[oY + bl * 8 + 4] = 1.0925484305920792f * uy * uz;
                    sm[oY + bl * 8 + 5] = 0.31539156525252005f * (2.0f * uz * uz - ux * ux - uy * uy);
                    sm[oY + bl * 8 + 6] = 1.0925484305920792f * ux * uz;
                    sm[oY + bl * 8 + 7] = 0.5462742152960396f * (ux * ux - uy * uy);
                }
            }
        }
    }
    __syncthreads();

    // ---------------- P1+P2 merged (independent: h from bas; T from f/Y) ---
    for (int idx = tid; idx < NS * 32; idx += 256) {
        int bl = idx >> 5, j = idx & 31;
        float su = 0.0f;
#pragma unroll
        for (int k = 0; k < NBASIS; ++k)
            su += sm[oBas + bl * NBASIS + k] * w0g[k * HHID + j];
        sm[oH + idx] = relu_r(su * ISQ10 + b0g[j]);
    }
    if constexpr (LAYER == 0) {
        for (int idx = tid; idx < NS * 16; idx += 256) {
            int loc = idx >> 4, c = idx & 15;
            sm[oT + loc * TSTR + c] = 0.28209479177387814f * sm[oF0 + loc * 16 + c];
        }
#pragma unroll
        for (int i2 = 0; i2 < 3; ++i2)
            for (int idx = tid; idx < NS * 16; idx += 256) {
                int loc = idx >> 4, v = idx & 15;
                sm[oT + loc * TSTR + 16 + i2 * 16 + v] =
                    sm[oY + loc * 8 + i2] * sm[oF0 + loc * 16 + v] * 0.5773502691896258f;
            }
    } else {
        for (int idx = tid; idx < NS * 16; idx += 256) {
            int loc = idx >> 4, c = idx & 15;
            sm[oT + loc * TSTR + c] = 0.28209479177387814f * sm[oF0 + loc * 16 + c];
        }
        for (int idx = tid; idx < NS * 8; idx += 256) {
            int loc = idx >> 3, u = idx & 7;
            const float* Yb = &sm[oY + loc * 8];
            const float* fT = &sm[oF1 + loc * 24];
            sm[oT + loc * TSTR + 16 + u] =
                (fT[u] * Yb[0] + fT[8 + u] * Yb[1] + fT[16 + u] * Yb[2]) * 0.5773502691896258f;
        }
#pragma unroll
        for (int i2 = 0; i2 < 3; ++i2)
            for (int idx = tid; idx < NS * 16; idx += 256) {
                int loc = idx >> 4, v = idx & 15;
                sm[oT + loc * TSTR + 24 + i2 * 16 + v] =
                    sm[oY + loc * 8 + i2] * sm[oF0 + loc * 16 + v] * 0.5773502691896258f;
            }
        for (int idx = tid; idx < NS * 24; idx += 256) {
            int loc = idx / 24, j = idx - loc * 24;
            sm[oT + loc * TSTR + 72 + j] =
                sm[oF1 + loc * 24 + j] * (0.28209479177387814f * 0.5773502691896258f);
        }
#pragma unroll
        for (int i2 = 0; i2 < 3; ++i2) {
            const int i1 = (i2 + 1) % 3, i3 = (i2 + 2) % 3;
            for (int idx = tid; idx < NS * 8; idx += 256) {
                int loc = idx >> 3, u = idx & 7;
                const float* Yb = &sm[oY + loc * 8];
                const float* fT = &sm[oF1 + loc * 24];
                sm[oT + loc * TSTR + 96 + i2 * 8 + u] =
                    (fT[i1 * 8 + u] * Yb[i3] - fT[i3 * 8 + u] * Yb[i1]) * 0.4082482904638631f;
            }
        }
#pragma unroll
        for (int i2 = 0; i2 < 3; ++i2)
            for (int idx = tid; idx < NS * 8; idx += 256) {
                int loc = idx >> 3, u = idx & 7;
                const float* Yb = &sm[oY + loc * 8];
                const float* fT = &sm[oF1 + loc * 24];
                const float D  = 0.31622776601683794f;
                const float Bc = 0.18257418583505536f;
                float f0v = fT[u], f1v = fT[8 + u], f2v = fT[16 + u];
                float Y20 = Yb[3], Y21 = Yb[4], Y22 = Yb[5], Y23 = Yb[6], Y24 = Yb[7];
                float val;
                if (i2 == 0)      val = D * (Y20 * f2v + Y21 * f1v) - (Bc * Y22 + D * Y24) * f0v;
                else if (i2 == 1) val = D * (Y21 * f0v + Y23 * f2v) + 2.0f * Bc * Y22 * f1v;
                else              val = D * (Y20 * f0v + Y23 * f1v + Y24 * f2v) - Bc * Y22 * f2v;
                sm[oT + loc * TSTR + 120 + i2 * 8 + u] = val;
            }
    }
    __syncthreads();

    // ---------------- P3: M update, register tile R x C (single pass) ------
    float acc[R][C];
#pragma unroll
    for (int rr = 0; rr < R; ++rr)
#pragma unroll
        for (int cc = 0; cc < C; ++cc) acc[rr][cc] = 0.0f;

    if constexpr (LAYER == 0) {
        const int hr = tid >> 4, cg = tid & 15;
#pragma unroll 4
        for (int bl = 0; bl < NS; ++bl) {
            float2 hv = *(const float2*)&sm[oH + bl * 32 + hr * 2];
            float4 tv = *(const float4*)&sm[oT + bl * 64 + cg * 4];
            float hvv[2] = {hv.x, hv.y};
            float tvv[4] = {tv.x, tv.y, tv.z, tv.w};
#pragma unroll
            for (int rr = 0; rr < 2; ++rr)
#pragma unroll
                for (int cc = 0; cc < 4; ++cc) acc[rr][cc] += hvv[rr] * tvv[cc];
        }
    } else {
        const int hr = tid >> 5, cg = tid & 31;
#pragma unroll 4
        for (int bl = 0; bl < NS; ++bl) {
            float4 hv = *(const float4*)&sm[oH + bl * 32 + hr * 4];
            const float* tp = &sm[oT + bl * TSTR + cg * 5];
            float hvv[4] = {hv.x, hv.y, hv.z, hv.w};
            float t0 = tp[0], t1 = tp[1], t2 = tp[2], t3 = tp[3], t4 = tp[4];
#pragma unroll
            for (int rr = 0; rr < 4; ++rr) {
                acc[rr][0] += hvv[rr] * t0;
                acc[rr][1] += hvv[rr] * t1;
                acc[rr][2] += hvv[rr] * t2;
                acc[rr][3] += hvv[rr] * t3;
                acc[rr][4] += hvv[rr] * t4;
            }
        }
    }
    __syncthreads();   // all T/h reads done before M overwrites region

    {
        const int hr = (LAYER == 0) ? (tid >> 4) : (tid >> 5);
        const int cg = (LAYER == 0) ? (tid & 15) : (tid & 31);
#pragma unroll
        for (int rr = 0; rr < R; ++rr)
#pragma unroll
            for (int cc = 0; cc < C; ++cc) {
                int col = cg * C + cc;
                if (col < TC) sm[(hr * R + rr) * MSTRE + col] = acc[rr][cc];
            }
    }
    __syncthreads();

    // ---------------- P4: epilogue, float4-vectorized -----------------------
    constexpr int NITEM = NOUT * 32;
    for (int rp = 0; rp < NITEM / 256; ++rp) {
        int idx = rp * 256 + tid;
        int h = idx / NOUT, o = idx - h * NOUT;
        const float* wr = &wout[h * TW];
        const float* mr = &sm[h * MSTRE];
        float U;
        if constexpr (LAYER == 0) {
            const float sc = I32 * 0.25f;
            float accv;
            if (o < 24) {
                const float4* w4 = (const float4*)(wr + o * 16);
                const float4* m4 = (const float4*)(mr);
                accv = dot4(w4[0], m4[0]) + dot4(w4[1], m4[1])
                     + dot4(w4[2], m4[2]) + dot4(w4[3], m4[3]);
            } else {
                int j = o - 24, u = j & 7, i2 = j >> 3;
                const float4* w4 = (const float4*)(wr + 384 + u * 16);
                const float4* m4 = (const float4*)(mr + 16 + i2 * 16);
                accv = dot4(w4[0], m4[0]) + dot4(w4[1], m4[1])
                     + dot4(w4[2], m4[2]) + dot4(w4[3], m4[3]);
            }
            U = accv * sc;
        } else if constexpr (LAYER == 1) {
            float aA, aB;
            if (o < 24) {
                const float4* w4 = (const float4*)(wr + o * 16);
                const float4* m4 = (const float4*)(mr);
                aA = dot4(w4[0], m4[0]) + dot4(w4[1], m4[1])
                   + dot4(w4[2], m4[2]) + dot4(w4[3], m4[3]);
                const float4* w8 = (const float4*)(wr + 384 + o * 8);
                const float4* m8 = (const float4*)(mr + 16);
                aB = dot4(w8[0], m8[0]) + dot4(w8[1], m8[1]);
                U = (aA * I32 + aB * 0.25f) * I32;
            } else {
                int j = o - 24, u = j & 7, i2 = j >> 3;
                const float4* w4 = (const float4*)(wr + 576 + u * 16);
                const float4* m4 = (const float4*)(mr + 24 + i2 * 16);
                aA = dot4(w4[0], m4[0]) + dot4(w4[1], m4[1])
                   + dot4(w4[2], m4[2]) + dot4(w4[3], m4[3]);
                const float4* wB0 = (const float4*)(wr + 704 + u * 8);
                const float4* wB1 = (const float4*)(wr + 768 + u * 8);
                const float4* wB2 = (const float4*)(wr + 832 + u * 8);
                const float4* mB0 = (const float4*)(mr + 72 + i2 * 8);
                const float4* mB1 = (const float4*)(mr + 96 + i2 * 8);
                const float4* mB2 = (const float4*)(mr + 120 + i2 * 8);
                aB = dot4(wB0[0], mB0[0]) + dot4(wB0[1], mB0[1])
                   + dot4(wB1[0], mB1[0]) + dot4(wB1[1], mB1[1])
                   + dot4(wB2[0], mB2[0]) + dot4(wB2[1], mB2[1]);
                U = (aA * 0.125f + aB * I32) * I32;
            }
        } else {  // LAYER == 2
            float aA, aB;
            if (o < 2) {
                const float4* w4 = (const float4*)(wr + o * 16);
                const float4* m4 = (const float4*)(mr);
                aA = dot4(w4[0], m4[0]) + dot4(w4[1], m4[1])
                   + dot4(w4[2], m4[2]) + dot4(w4[3], m4[3]);
                const float4* w8 = (const float4*)(wr + 32 + o * 8);
                const float4* m8 = (const float4*)(mr + 16);
                aB = dot4(w8[0], m8[0]) + dot4(w8[1], m8[1]);
                U = (aA * I32 + aB * 0.25f) * I32;
            } else {
                int j = o - 2, u = j & 1, i2 = j >> 1;
                const float4* w4 = (const float4*)(wr + 48 + u * 16);
                const float4* m4 = (const float4*)(mr + 24 + i2 * 16);
                aA = dot4(w4[0], m4[0]) + dot4(w4[1], m4[1])
                   + dot4(w4[2], m4[2]) + dot4(w4[3], m4[3]);
                const float4* wB0 = (const float4*)(wr + 80 + u * 8);
                const float4* wB1 = (const float4*)(wr + 96 + u * 8);
                const float4* wB2 = (const float4*)(wr + 112 + u * 8);
                const float4* mB0 = (const float4*)(mr + 72 + i2 * 8);
                const float4* mB1 = (const float4*)(mr + 96 + i2 * 8);
                const float4* mB2 = (const float4*)(mr + 120 + i2 * 8);
                aB = dot4(wB0[0], mB0[0]) + dot4(wB0[1], mB0[1])
                   + dot4(wB1[0], mB1[0]) + dot4(wB1[1], mB1[1])
                   + dot4(wB2[0], mB2[0]) + dot4(wB2[1], mB2[1]);
                U = (aA * 0.125f + aB * I32) * I32;
            }
        }
        sm[oU + o * 33 + h] = U;
    }
    __syncthreads();

    if (tid < NOUT) {
        float su = 0.0f;
#pragma unroll
        for (int h = 0; h < 32; ++h) su += sm[oU + tid * 33 + h];
        part[blk * NOUT + tid] = su;
    }
}

// ---------------------------------------------------------------------------
// Final sum: out[atom][2*4] interleaved from 8 split partials of layer 2.
// ---------------------------------------------------------------------------
__global__ __launch_bounds__(256) void tfn_fin(
    const float* __restrict__ part2, float* __restrict__ out)
{
    int t = blockIdx.x * 256 + threadIdx.x;  // < BB*NN*8
    int atom = t >> 3, o = t & 7;
    const float* p = &part2[atom * SPLIT * 8];
    float su = ((p[o] + p[8 + o]) + (p[16 + o] + p[24 + o]))
             + ((p[32 + o] + p[40 + o]) + (p[48 + o] + p[56 + o]));
    int pos;
    if (o < 2) pos = o * 4;
    else { int j = o - 2; int i2 = j >> 1, u = j & 1; pos = u * 4 + 1 + i2; }
    out[atom * 8 + pos] = su;
}

// ---------------------------------------------------------------------------
// Fallback: verified round-1 monolithic kernel (used only if ws too small).
// ---------------------------------------------------------------------------
template <int LAYER>
__global__ __launch_bounds__(256) void tfn_layer_mono(
    const float* __restrict__ geo,
    const float* __restrict__ fin0,
    const float* __restrict__ fin1,
    const float* __restrict__ w0,
    const float* __restrict__ b0g,
    const float* __restrict__ wout,
    float* __restrict__ o0,
    float* __restrict__ o1)
{
    constexpr int TC   = (LAYER == 0) ? 64 : 144;
    constexpr int TW   = (LAYER == 0) ? 512 : (LAYER == 1 ? 896 : 128);
    constexpr int CPT  = TC / 8;
    constexpr int CPTT = TC / 16;

    const int tid = threadIdx.x;
    const int blk = blockIdx.x;
    const int z = blk / NN, a = blk % NN;

    __shared__ float geoL[NN * 3];
    __shared__ float f0L[NN * 16];
    __shared__ float f1L[(LAYER == 0) ? 1 : (NN * 24)];
    __shared__ float w0L[NBASIS * HHID];
    __shared__ float b0L[HHID];
    __shared__ float YC[16 * 8];
    __shared__ float basC[16 * NBASIS];
    __shared__ float hC[16 * HHID];
    __shared__ float tC[16 * TC];
    __shared__ float Mlds[HHID * TC];
    __shared__ float outS[32];

    const float s = S_SCALE;

    for (int i = tid; i < NN * 3; i += 256) geoL[i] = geo[z * NN * 3 + i];
    for (int i = tid; i < NN * 16; i += 256) {
        float v = fin0[z * NN * 16 + i];
        if (LAYER == 0) v *= s;
        f0L[i] = v;
    }
    if constexpr (LAYER != 0) {
        for (int i = tid; i < NN * 24; i += 256) f1L[i] = fin1[z * NN * 24 + i];
    }
    for (int i = tid; i < NBASIS * HHID; i += 256) w0L[i] = w0[i];
    if (tid < HHID) b0L[tid] = b0g[tid];
    __syncthreads();

    const float ax = geoL[a * 3 + 0], ay = geoL[a * 3 + 1], az = geoL[a * 3 + 2];

    float Macc[CPT];
#pragma unroll
    for (int j = 0; j < CPT; ++j) Macc[j] = 0.0f;
    const int hh  = tid >> 3;
    const int cg0 = (tid & 7) * CPT;

    for (int cb = 0; cb < NN / 16; ++cb) {
        {
            const int bl = tid & 15, item = tid >> 4;
            const int b = cb * 16 + bl;
            float rx = ax - geoL[b * 3 + 0];
            float ry = ay - geoL[b * 3 + 1];
            float rz = az - geoL[b * 3 + 2];
            float r = sqrtf(rx * rx + ry * ry + rz * rz + 1e-12f);
            float inv = 1.0f / fmaxf(r, 1e-6f);
            float ux = rx * inv, uy = ry * inv, uz = rz * inv;
            if (item < NBASIS) {
                float dg = r * 2.25f - (float)item;
                float bas = 0.0f;
                if (fabsf(dg) < 1.0f) {
                    float cc = cosf(1.5707963267948966f * dg);
                    bas = cc * cc;
                }
                basC[bl * NBASIS + item] = bas;
            } else if (item == 10) {
                YC[bl * 8 + 0] = 0.4886025119029199f * uy;
                YC[bl * 8 + 1] = 0.4886025119029199f * uz;
                YC[bl * 8 + 2] = 0.4886025119029199f * ux;
            } else if (item == 11) {
                YC[bl * 8 + 3] = 1.0925484305920792f * ux * uy;
                YC[bl * 8 + 4] = 1.0925484305920792f * uy * uz;
                YC[bl * 8 + 5] = 0.31539156525252005f * (2.0f * uz * uz - ux * ux - uy * uy);
                YC[bl * 8 + 6] = 1.0925484305920792f * ux * uz;
                YC[bl * 8 + 7] = 0.5462742152960396f * (ux * ux - uy * uy);
            }
        }
        __syncthreads();

#pragma unroll
        for (int rep = 0; rep < 2; ++rep) {
            int idx = tid + rep * 256;
            int bl = idx >> 5, h2 = idx & 31;
            float su = 0.0f;
#pragma unroll
            for (int k = 0; k < NBASIS; ++k) su += basC[bl * NBASIS + k] * w0L[k * HHID + h2];
            hC[bl * HHID + h2] = relu_r(su * ISQ10 + b0L[h2]);
        }

        {
            const int bl = tid >> 4, cg = tid & 15;
            const int b = cb * 16 + bl;
            const float* Yb = &YC[bl * 8];
#pragma unroll
            for (int jj = 0; jj < CPTT; ++jj) {
                int c = cg * CPTT + jj;
                float val;
                if constexpr (LAYER == 0) {
                    if (c < 16) {
                        val = 0.28209479177387814f * f0L[b * 16 + c];
                    } else {
                        int q = c - 16, v = q / 3, i2 = q % 3;
                        val = Yb[i2] * f0L[b * 16 + v] * 0.5773502691896258f;
                    }
                } else {
                    if (c < 16) {
                        val = 0.28209479177387814f * f0L[b * 16 + c];
                    } else if (c < 24) {
                        int v = c - 16;
                        const float* f = &f1L[(b * 8 + v) * 3];
                        val = (f[0] * Yb[0] + f[1] * Yb[1] + f[2] * Yb[2]) * 0.5773502691896258f;
                    } else if (c < 72) {
                        int q = c - 24, v = q / 3, i2 = q % 3;
                        val = Yb[i2] * f0L[b * 16 + v] * 0.5773502691896258f;
                    } else if (c < 96) {
                        int q = c - 72, v = q / 3, i2 = q % 3;
                        val = f1L[(b * 8 + v) * 3 + i2] * (0.28209479177387814f * 0.5773502691896258f);
                    } else if (c < 120) {
                        int q = c - 96, v = q / 3, i2 = q % 3;
                        const float* f = &f1L[(b * 8 + v) * 3];
                        int i1 = (i2 + 1) % 3, i3 = (i2 + 2) % 3;
                        val = (f[i1] * Yb[i3] - f[i3] * Yb[i1]) * 0.4082482904638631f;
                    } else {
                        int q = c - 120, v = q / 3, i2 = q % 3;
                        const float* f = &f1L[(b * 8 + v) * 3];
                        const float D = 0.31622776601683794f;
                        const float Bc = 0.18257418583505536f;
                        float Y20 = Yb[3], Y21 = Yb[4], Y22 = Yb[5], Y23 = Yb[6], Y24 = Yb[7];
                        if (i2 == 0)      val = D * (Y20 * f[2] + Y21 * f[1]) - (Bc * Y22 + D * Y24) * f[0];
                        else if (i2 == 1) val = D * (Y21 * f[0] + Y23 * f[2]) + 2.0f * Bc * Y22 * f[1];
                        else              val = D * (Y20 * f[0] + Y23 * f[1] + Y24 * f[2]) - Bc * Y22 * f[2];
                    }
                }
                tC[bl * TC + c] = val;
            }
        }
        __syncthreads();

#pragma unroll 4
        for (int bl = 0; bl < 16; ++bl) {
            float hv = hC[bl * HHID + hh];
#pragma unroll
            for (int j = 0; j < CPT; ++j) Macc[j] += hv * tC[bl * TC + cg0 + j];
        }
        __syncthreads();
    }

#pragma unroll
    for (int j = 0; j < CPT; ++j) Mlds[hh * TC + cg0 + j] = Macc[j];
    __syncthreads();

    const float i32 = I32;

    if constexpr (LAYER == 0) {
        const float sc = i32 * 0.25f;
        float o1v = 0.0f;
        if (tid < 24) {
            float acc = 0.0f;
            for (int h2 = 0; h2 < 32; ++h2) {
                const float* wr = &wout[h2 * TW + tid * 16];
                const float* mr = &Mlds[h2 * TC];
#pragma unroll
                for (int v = 0; v < 16; ++v) acc += wr[v] * mr[v];
            }
            outS[tid] = acc * sc;
        } else if (tid >= 32 && tid < 56) {
            int idx = tid - 32, u = idx / 3, i2 = idx % 3;
            float acc = 0.0f;
            for (int h2 = 0; h2 < 32; ++h2) {
                const float* wr = &wout[h2 * TW + 384 + u * 16];
                const float* mr = &Mlds[h2 * TC + 16 + i2];
#pragma unroll
                for (int v = 0; v < 16; ++v) acc += wr[v] * mr[v * 3];
            }
            o1v = acc * sc;
        }
        __syncthreads();
        if (tid < 16) {
            o0[(z * NN + a) * 16 + tid] = relu_r(outS[tid]) * s;
        } else if (tid >= 32 && tid < 56) {
            int idx = tid - 32, u = idx / 3, i2 = idx % 3;
            float g = sigmoid_r(outS[16 + u]);
            o1[((z * NN + a) * 8 + u) * 3 + i2] = o1v * g * s;
        }
    } else if constexpr (LAYER == 1) {
        float o1v = 0.0f;
        if (tid < 24) {
            float aA = 0.0f, aB = 0.0f;
            for (int h2 = 0; h2 < 32; ++h2) {
                const float* wr = &wout[h2 * TW];
                const float* mr = &Mlds[h2 * TC];
#pragma unroll
                for (int v = 0; v < 16; ++v) aA += wr[tid * 16 + v] * mr[v];
#pragma unroll
                for (int v = 0; v < 8; ++v) aB += wr[384 + tid * 8 + v] * mr[16 + v];
            }
            outS[tid] = (aA * i32 + aB * 0.25f) * i32;
        } else if (tid >= 32 && tid < 56) {
            int idx = tid - 32, u = idx / 3, i2 = idx % 3;
            float aA = 0.0f, aB = 0.0f;
            for (int h2 = 0; h2 < 32; ++h2) {
                const float* wr = &wout[h2 * TW];
                const float* mr = &Mlds[h2 * TC];
#pragma unroll
                for (int v = 0; v < 16; ++v) aA += wr[576 + u * 16 + v] * mr[24 + v * 3 + i2];
#pragma unroll
                for (int v = 0; v < 8; ++v)
                    aB += wr[704 + u * 8 + v] * mr[72 + v * 3 + i2]
                        + wr[768 + u * 8 + v] * mr[96 + v * 3 + i2]
                        + wr[832 + u * 8 + v] * mr[120 + v * 3 + i2];
            }
            o1v = (aA * 0.125f + aB * i32) * i32;
        }
        __syncthreads();
        if (tid < 16) {
            o0[(z * NN + a) * 16 + tid] = relu_r(outS[tid]) * s;
        } else if (tid >= 32 && tid < 56) {
            int idx = tid - 32, u = idx / 3, i2 = idx % 3;
            float g = sigmoid_r(outS[16 + u]);
            o1[((z * NN + a) * 8 + u) * 3 + i2] = o1v * g * s;
        }
    } else {
        if (tid < 2) {
            float aA = 0.0f, aB = 0.0f;
            for (int h2 = 0; h2 < 32; ++h2) {
                const float* wr = &wout[h2 * TW];
                const float* mr = &Mlds[h2 * TC];
#pragma unroll
                for (int v = 0; v < 16; ++v) aA += wr[tid * 16 + v] * mr[v];
#pragma unroll
                for (int v = 0; v < 8; ++v) aB += wr[32 + tid * 8 + v] * mr[16 + v];
            }
            o0[(z * NN + a) * 8 + tid * 4] = (aA * i32 + aB * 0.25f) * i32;
        } else if (tid >= 32 && tid < 38) {
            int idx = tid - 32, u = idx / 3, i2 = idx % 3;
            float aA = 0.0f, aB = 0.0f;
            for (int h2 = 0; h2 < 32; ++h2) {
                const float* wr = &wout[h2 * TW];
                const float* mr = &Mlds[h2 * TC];
#pragma unroll
                for (int v = 0; v < 16; ++v) aA += wr[48 + u * 16 + v] * mr[24 + v * 3 + i2];
#pragma unroll
                for (int v = 0; v < 8; ++v)
                    aB += wr[80 + u * 8 + v] * mr[72 + v * 3 + i2]
                        + wr[96 + u * 8 + v] * mr[96 + v * 3 + i2]
                        + wr[112 + u * 8 + v] * mr[120 + v * 3 + i2];
            }
            o0[(z * NN + a) * 8 + u * 4 + 1 + i2] = (aA * 0.125f + aB * i32) * i32;
        }
    }
}

extern "C" void kernel_launch(void* const* d_in, const int* in_sizes, int n_in,
                              void* d_out, int out_size, void* d_ws, size_t ws_size,
                              hipStream_t stream) {
    const float* features = (const float*)d_in[0];
    const float* geometry = (const float*)d_in[1];
    const float* c0w0   = (const float*)d_in[2];
    const float* c0b0   = (const float*)d_in[3];
    const float* c0wout = (const float*)d_in[4];
    const float* c1w0   = (const float*)d_in[5];
    const float* c1b0   = (const float*)d_in[6];
    const float* c1wout = (const float*)d_in[7];
    const float* c2w0   = (const float*)d_in[8];
    const float* c2b0   = (const float*)d_in[9];
    const float* c2wout = (const float*)d_in[10];
    float* out = (float*)d_out;

    float* ws = (float*)d_ws;
    const size_t NBLK  = (size_t)BB * NN * SPLIT;                // 3072
    const size_t NATOM = (size_t)BB * NN;                        // 384
    const size_t need  = NBLK * 48 * 2 + NBLK * 8 + NATOM * 40 * 2;

    if (ws_size >= need * sizeof(float)) {
        float* partA = ws;
        float* partB = partA + NBLK * 48;
        float* part2 = partB + NBLK * 48;
        float* fa0A  = part2 + NBLK * 8;
        float* fa1A  = fa0A + NATOM * 16;
        float* fa0B  = fa1A + NATOM * 24;
        float* fa1B  = fa0B + NATOM * 16;

        dim3 g1((unsigned)NBLK), blk(256);
        dim3 gact((unsigned)((NATOM * 40 + 255) / 256));
        hipLaunchKernelGGL((tfn_s1<0>), g1, blk, 0, stream,
                           features, nullptr, geometry, c0w0, c0b0, c0wout, partA);
        hipLaunchKernelGGL(tfn_act, gact, blk, 0, stream, partA, fa0A, fa1A);
        hipLaunchKernelGGL((tfn_s1<1>), g1, blk, 0, stream,
                           fa0A, fa1A, geometry, c1w0, c1b0, c1wout, partB);
        hipLaunchKernelGGL(tfn_act, gact, blk, 0, stream, partB, fa0B, fa1B);
        hipLaunchKernelGGL((tfn_s1<2>), g1, blk, 0, stream,
                           fa0B, fa1B, geometry, c2w0, c2b0, c2wout, part2);
        hipLaunchKernelGGL(tfn_fin, dim3(BB * NN * 8 / 256), blk, 0, stream,
                           part2, out);
    } else {
        float* f0a = ws;
        float* f1a = f0a + BB * NN * 16;
        float* f0b = f1a + BB * NN * 24;
        float* f1b = f0b + BB * NN * 16;
        dim3 grid(BB * NN), blk(256);
        hipLaunchKernelGGL((tfn_layer_mono<0>), grid, blk, 0, stream,
                           geometry, features, nullptr, c0w0, c0b0, c0wout, f0a, f1a);
        hipLaunchKernelGGL((tfn_layer_mono<1>), grid, blk, 0, stream,
                           geometry, f0a, f1a, c1w0, c1b0, c1wout, f0b, f1b);
        hipLaunchKernelGGL((tfn_layer_mono<2>), grid, blk, 0, stream,
                           geometry, f0b, f1b, c2w0, c2b0, c2wout, out, nullptr);
    }
}